// Round 16
// baseline (152.614 us; speedup 1.0000x reference)
//
#include <hip/hip_runtime.h>
#include <hip/hip_bf16.h>

typedef __hip_bfloat16 bf16;
typedef __attribute__((ext_vector_type(2))) float f32x2;
#define EPSF 1e-5f

// ---------------- K1: comp = relu(bn(conv1x1(x))) (R9 form) ----------------
__global__ void k1_comp(const float* __restrict__ x, const float* __restrict__ w,
                        const float* __restrict__ gamma, const float* __restrict__ beta,
                        const float* __restrict__ mean, const float* __restrict__ var,
                        float* __restrict__ comp) {
    __shared__ float shx[2][32 * 64];           // 16 KB
    __shared__ float shw[256 * 20];             // 20 KB, [ic][oc_local] pitch 20
    const int pxt = blockIdx.x;                 // 0..63
    const int ocg = blockIdx.y;                 // 0..3 (16 oc per block)
    const int b   = blockIdx.z;
    const int tid  = threadIdx.x;
    const int wave = tid >> 6, lane = tid & 63;
    const int oc0l = wave * 4;                  // local oc base (wave-uniform)
    const int px0 = pxt << 6;
    const float* xb = x + b * (256 * 4096) + px0;

    const int f40 = tid * 2, f41 = tid * 2 + 1;
    const int r0 = f40 >> 4, c0 = f40 & 15;
    const int r1 = f41 >> 4, c1 = f41 & 15;

    float wtmp[16];
    #pragma unroll
    for (int k = 0; k < 16; ++k)
        wtmp[k] = w[(ocg * 16 + k) * 256 + tid];        // 16 coalesced 256B loads
    float4 xa = *(const float4*)(xb + r0 * 4096 + c0 * 4);
    float4 xc = *(const float4*)(xb + r1 * 4096 + c1 * 4);

    #pragma unroll
    for (int k = 0; k < 16; ++k)
        shw[tid * 20 + k] = wtmp[k];
    *(float4*)(&shx[0][r0 * 64 + c0 * 4]) = xa;
    *(float4*)(&shx[0][r1 * 64 + c1 * 4]) = xc;
    __syncthreads();

    float acc[4] = {0.f, 0.f, 0.f, 0.f};

    for (int icc = 0; icc < 8; ++icc) {
        const int buf = icc & 1;
        float4 na, nc;                          // T14: issue before compute
        if (icc < 7) {
            na = *(const float4*)(xb + ((icc + 1) * 32 + r0) * 4096 + c0 * 4);
            nc = *(const float4*)(xb + ((icc + 1) * 32 + r1) * 4096 + c1 * 4);
        }
        #pragma unroll 8
        for (int ic_l = 0; ic_l < 32; ++ic_l) {
            float xv = shx[buf][ic_l * 64 + lane];
            float4 wv = *(const float4*)(&shw[(icc * 32 + ic_l) * 20 + oc0l]);
            acc[0] += xv * wv.x;
            acc[1] += xv * wv.y;
            acc[2] += xv * wv.z;
            acc[3] += xv * wv.w;
        }
        if (icc < 7) {                          // write-late
            *(float4*)(&shx[buf ^ 1][r0 * 64 + c0 * 4]) = na;
            *(float4*)(&shx[buf ^ 1][r1 * 64 + c1 * 4]) = nc;
        }
        __syncthreads();
    }
    #pragma unroll
    for (int m = 0; m < 4; ++m) {
        int mo = ocg * 16 + oc0l + m;
        float s = gamma[mo] * rsqrtf(var[mo] + EPSF);
        float r = acc[m] * s + (beta[mo] - mean[mo] * s);
        comp[(b * 64 + mo) * 4096 + px0 + lane] = fmaxf(r, 0.f);
    }
}

// ---------------- K2: split-K conv3x3 partials ----------
// R15: 10 oc per block (was 5), tile 4 rows x 64 cols, 128 threads, grid
// (16,40,2) = 1280 blocks -> 5 blocks/CU balance preserved. Rationale (R13
// measured: VALU/LDS-issue bound, 82% VALUBusy): the t-window LDS reads and
// the staging amortize over 2x the FMA work -> total ds_read count and total
// staging across the grid HALVE while FMA stays constant. Per-accumulator
// ic/tap order unchanged -> bit-identical output. LDS 12.7 KB.
__global__ void k2_enc_part(const float* __restrict__ comp, const float* __restrict__ w,
                            float* __restrict__ encp) {
    __shared__ float sh[8 * 396];               // 8 planes of 6x66 = 12.7 KB
    const int tile = blockIdx.x;                // 0..15: 16 row-tiles of 4 rows
    const int og   = blockIdx.y >> 2;           // 0..9 (10 oc each)
    const int icc  = blockIdx.y & 3;            // 0..3  (16 ic each)
    const int b    = blockIdx.z;
    const int ty0 = tile << 2;                  // 0,4,...,60
    const int tid = threadIdx.x;                // 0..127
    const int tx = tid & 31, ty = tid >> 5;     // col-pair 0..31, row 0..3
    const int o0 = og * 10;

    // hoisted staging offsets: 3168 slots / 128 thr -> 25 per thread
    int goff[25];
    #pragma unroll
    for (int k = 0; k < 25; ++k) {
        int idx = tid + k * 128;
        int off = -1;
        if (idx < 3168) {
            int ic_l = idx / 396;
            int rem  = idx - ic_l * 396;
            int r = rem / 66;
            int c = rem - r * 66;
            int gy = ty0 + r - 1;
            int gx = c - 1;
            if (gy >= 0 && gy < 64 && gx >= 0 && gx < 64)
                off = (ic_l << 12) + (gy << 6) + gx;
        }
        goff[k] = off;
    }

    f32x2 acc2[10];
    #pragma unroll
    for (int i = 0; i < 10; ++i) acc2[i] = (f32x2){0.f, 0.f};

    for (int ics = 0; ics < 2; ++ics) {
        if (ics) __syncthreads();
        const float* cb = comp + (b * 64 + icc * 16 + ics * 8) * 4096;
        #pragma unroll
        for (int k = 0; k < 25; ++k) {
            int idx = tid + k * 128;
            float v = 0.f;
            if (goff[k] >= 0) v = cb[goff[k]];
            if (idx < 3168) sh[idx] = v;
        }
        __syncthreads();

        #pragma unroll 2
        for (int ic_l = 0; ic_l < 8; ++ic_l) {
            const float* base = sh + ic_l * 396 + ty * 66 + 2 * tx;
            float t[3][4];
            #pragma unroll
            for (int dy = 0; dy < 3; ++dy)
                #pragma unroll
                for (int dx = 0; dx < 4; ++dx)
                    t[dy][dx] = base[dy * 66 + dx];
            f32x2 t2[3][3];
            #pragma unroll
            for (int dy = 0; dy < 3; ++dy)
                #pragma unroll
                for (int dx = 0; dx < 3; ++dx)
                    t2[dy][dx] = (f32x2){t[dy][dx], t[dy][dx + 1]};
            const int ic = icc * 16 + ics * 8 + ic_l;
            #pragma unroll
            for (int o_l = 0; o_l < 10; ++o_l) {
                const float* wp = w + ((o0 + o_l) * 64 + ic) * 9;   // uniform -> s_load
                f32x2 a = acc2[o_l];
                #pragma unroll
                for (int dy = 0; dy < 3; ++dy)
                    #pragma unroll
                    for (int dx = 0; dx < 3; ++dx)
                        a += wp[dy * 3 + dx] * t2[dy][dx];
                acc2[o_l] = a;
            }
        }
    }
    const int pix = ((ty0 + ty) << 6) + 2 * tx;
    #pragma unroll
    for (int o_l = 0; o_l < 10; ++o_l) {
        float2 v = {acc2[o_l].x, acc2[o_l].y};
        *(float2*)(&encp[((icc * 2 + b) * 100 + o0 + o_l) * 4096 + pix]) = v;
    }
}

// ---------------- K3: sum partials + BN + pixel-shuffle + softmax (R8) -------
__global__ void k3_softmax(const float* __restrict__ encp,
                           const float* __restrict__ gamma, const float* __restrict__ beta,
                           const float* __restrict__ mean, const float* __restrict__ var,
                           bf16* __restrict__ Wsm) {
    __shared__ float red[2][5][64];
    const int tid  = threadIdx.x;
    const int lane = tid & 63, wv = tid >> 6;   // wv 0..4
    const int item = blockIdx.x * 64 + lane;    // 0..32767
    const int pos = item & 4095;
    const int g   = (item >> 12) & 3;           // block-uniform
    const int b   = item >> 14;                 // block-uniform
    const int kbase = wv * 5;                   // 0,5,10,15,20
    const size_t ICS = (size_t)200 * 4096;      // icc stride in encp

    float L[5][4];
    #pragma unroll
    for (int q = 0; q < 5; ++q) {               // branch-free: loads all hoist
        const int o = (kbase + q) * 4 + g;
        const float* ep = encp + ((size_t)b * 100 + o) * 4096 + pos;
        L[q][0] = ep[0];
        L[q][1] = ep[ICS];
        L[q][2] = ep[2 * ICS];
        L[q][3] = ep[3 * ICS];
    }
    float v[5];
    float mx = -1e30f;
    #pragma unroll
    for (int q = 0; q < 5; ++q) {
        const int o = (kbase + q) * 4 + g;
        float a = ((L[q][0] + L[q][1]) + L[q][2]) + L[q][3];
        float s = gamma[o] * rsqrtf(var[o] + EPSF);
        v[q] = a * s + (beta[o] - mean[o] * s);
        mx = fmaxf(mx, v[q]);
    }
    red[0][wv][lane] = mx;
    __syncthreads();
    mx = fmaxf(fmaxf(fmaxf(red[0][0][lane], red[0][1][lane]),
                     fmaxf(red[0][2][lane], red[0][3][lane])), red[0][4][lane]);
    float s = 0.f;
    #pragma unroll
    for (int q = 0; q < 5; ++q) { v[q] = __expf(v[q] - mx); s += v[q]; }
    red[1][wv][lane] = s;
    __syncthreads();
    s = (((red[1][0][lane] + red[1][1][lane]) + red[1][2][lane])
         + red[1][3][lane]) + red[1][4][lane];
    const float inv = 1.f / s;
    bf16* o_ = Wsm + ((size_t)(b * 4 + g) * 25 + kbase) * 4096 + pos;
    #pragma unroll
    for (int q = 0; q < 5; ++q) o_[q * 4096] = __float2bfloat16(v[q] * inv);
}

// ---------------- K4: weighted gather (R12 nt-store form, unchanged) ---------
__global__ void k4_gather(const float* __restrict__ x, const bf16* __restrict__ Wsm,
                          float* __restrict__ out) {
    __shared__ float4 patch[8 * 36];            // 4.6 KB
    const int tile   = blockIdx.x;              // 0..31: tileY 0..15, tileX 0..1
    const int cchunk = blockIdx.y;              // 0..31 (8 channels each)
    const int b      = blockIdx.z;
    const int ly0 = (tile >> 1) << 2;           // 0,4,...,60
    const int lx0 = (tile & 1) << 5;            // 0,32
    const int tid = threadIdx.x;
    const int ph = tid >> 7;
    const int r  = tid & 127;
    const int ly = r >> 5, lx = r & 31;
    const int yl = ly0 + ly, xl = lx0 + lx;

    float w0[25], w1[25];
    {
        const bf16* wp0 = Wsm + ((b * 4 + ph * 2    ) * 25) * 4096 + yl * 64 + xl;
        const bf16* wp1 = Wsm + ((b * 4 + ph * 2 + 1) * 25) * 4096 + yl * 64 + xl;
        #pragma unroll
        for (int k = 0; k < 25; ++k) {
            w0[k] = __bfloat162float(wp0[k * 4096]);
            w1[k] = __bfloat162float(wp1[k * 4096]);
        }
    }

    for (int cg = 0; cg < 2; ++cg) {
        const int c0 = cchunk * 8 + cg * 4;
        for (int idx = tid; idx < 8 * 36; idx += 256) {
            int pr = idx / 36, pc = idx - (idx / 36) * 36;
            int gy = ly0 - 2 + pr, gx = lx0 - 2 + pc;
            float4 v = {0.f, 0.f, 0.f, 0.f};
            if (gy >= 0 && gy < 64 && gx >= 0 && gx < 64) {
                const float* xp = x + ((b * 256 + c0) * 4096) + gy * 64 + gx;
                v.x = xp[0]; v.y = xp[4096]; v.z = xp[8192]; v.w = xp[12288];
            }
            patch[idx] = v;
        }
        __syncthreads();
        float4 a0 = {0.f, 0.f, 0.f, 0.f};
        float4 a1 = {0.f, 0.f, 0.f, 0.f};
        #pragma unroll
        for (int i = 0; i < 5; ++i) {
            #pragma unroll
            for (int j = 0; j < 5; ++j) {
                float4 xv = patch[(ly + i) * 36 + (lx + j)];
                float wa = w0[i * 5 + j], wb = w1[i * 5 + j];
                a0.x += wa * xv.x; a0.y += wa * xv.y; a0.z += wa * xv.z; a0.w += wa * xv.w;
                a1.x += wb * xv.x; a1.y += wb * xv.y; a1.z += wb * xv.z; a1.w += wb * xv.w;
            }
        }
        float* ob = out + (size_t)(b * 256 + c0) * 16384 + (2 * yl + ph) * 128 + 2 * xl;
        f32x2 s0 = {a0.x, a1.x};
        f32x2 s1 = {a0.y, a1.y};
        f32x2 s2 = {a0.z, a1.z};
        f32x2 s3 = {a0.w, a1.w};
        __builtin_nontemporal_store(s0, (f32x2*)(ob));
        __builtin_nontemporal_store(s1, (f32x2*)(ob + 16384));
        __builtin_nontemporal_store(s2, (f32x2*)(ob + 32768));
        __builtin_nontemporal_store(s3, (f32x2*)(ob + 49152));
        if (cg == 0) __syncthreads();
    }
}

extern "C" void kernel_launch(void* const* d_in, const int* in_sizes, int n_in,
                              void* d_out, int out_size, void* d_ws, size_t ws_size,
                              hipStream_t stream) {
    const float* x          = (const float*)d_in[0];
    const float* comp_w     = (const float*)d_in[1];
    const float* comp_gamma = (const float*)d_in[2];
    const float* comp_beta  = (const float*)d_in[3];
    const float* comp_mean  = (const float*)d_in[4];
    const float* comp_var   = (const float*)d_in[5];
    const float* enc_w      = (const float*)d_in[6];
    const float* enc_gamma  = (const float*)d_in[7];
    const float* enc_beta   = (const float*)d_in[8];
    const float* enc_mean   = (const float*)d_in[9];
    const float* enc_var    = (const float*)d_in[10];
    float* out = (float*)d_out;

    float* ws   = (float*)d_ws;
    float* comp = ws;                             // 2*64*4096    =  524288 floats
    float* encp = ws + 524288;                    // 4*2*100*4096 = 3276800 floats
    bf16*  Wsm  = (bf16*)(ws + 524288 + 3276800); // 2*4*25*4096 bf16

    k1_comp<<<dim3(64, 4, 2), dim3(256), 0, stream>>>(x, comp_w, comp_gamma, comp_beta,
                                                      comp_mean, comp_var, comp);
    k2_enc_part<<<dim3(16, 40, 2), dim3(128), 0, stream>>>(comp, enc_w, encp);
    k3_softmax<<<dim3(512), dim3(320), 0, stream>>>(encp, enc_gamma, enc_beta,
                                                    enc_mean, enc_var, Wsm);
    k4_gather<<<dim3(32, 32, 2), dim3(256), 0, stream>>>(x, Wsm, out);
}

// Round 17
// 137.352 us; speedup vs baseline: 1.1111x; 1.1111x over previous
//
#include <hip/hip_runtime.h>
#include <hip/hip_bf16.h>

typedef __hip_bfloat16 bf16;
typedef __attribute__((ext_vector_type(2))) float f32x2;
#define EPSF 1e-5f

// ---------------- K1: comp = relu(bn(conv1x1(x))) (R9 form) ----------------
__global__ void k1_comp(const float* __restrict__ x, const float* __restrict__ w,
                        const float* __restrict__ gamma, const float* __restrict__ beta,
                        const float* __restrict__ mean, const float* __restrict__ var,
                        float* __restrict__ comp) {
    __shared__ float shx[2][32 * 64];           // 16 KB
    __shared__ float shw[256 * 20];             // 20 KB, [ic][oc_local] pitch 20
    const int pxt = blockIdx.x;                 // 0..63
    const int ocg = blockIdx.y;                 // 0..3 (16 oc per block)
    const int b   = blockIdx.z;
    const int tid  = threadIdx.x;
    const int wave = tid >> 6, lane = tid & 63;
    const int oc0l = wave * 4;                  // local oc base (wave-uniform)
    const int px0 = pxt << 6;
    const float* xb = x + b * (256 * 4096) + px0;

    const int f40 = tid * 2, f41 = tid * 2 + 1;
    const int r0 = f40 >> 4, c0 = f40 & 15;
    const int r1 = f41 >> 4, c1 = f41 & 15;

    float wtmp[16];
    #pragma unroll
    for (int k = 0; k < 16; ++k)
        wtmp[k] = w[(ocg * 16 + k) * 256 + tid];        // 16 coalesced 256B loads
    float4 xa = *(const float4*)(xb + r0 * 4096 + c0 * 4);
    float4 xc = *(const float4*)(xb + r1 * 4096 + c1 * 4);

    #pragma unroll
    for (int k = 0; k < 16; ++k)
        shw[tid * 20 + k] = wtmp[k];
    *(float4*)(&shx[0][r0 * 64 + c0 * 4]) = xa;
    *(float4*)(&shx[0][r1 * 64 + c1 * 4]) = xc;
    __syncthreads();

    float acc[4] = {0.f, 0.f, 0.f, 0.f};

    for (int icc = 0; icc < 8; ++icc) {
        const int buf = icc & 1;
        float4 na, nc;                          // T14: issue before compute
        if (icc < 7) {
            na = *(const float4*)(xb + ((icc + 1) * 32 + r0) * 4096 + c0 * 4);
            nc = *(const float4*)(xb + ((icc + 1) * 32 + r1) * 4096 + c1 * 4);
        }
        #pragma unroll 8
        for (int ic_l = 0; ic_l < 32; ++ic_l) {
            float xv = shx[buf][ic_l * 64 + lane];
            float4 wv = *(const float4*)(&shw[(icc * 32 + ic_l) * 20 + oc0l]);
            acc[0] += xv * wv.x;
            acc[1] += xv * wv.y;
            acc[2] += xv * wv.z;
            acc[3] += xv * wv.w;
        }
        if (icc < 7) {                          // write-late
            *(float4*)(&shx[buf ^ 1][r0 * 64 + c0 * 4]) = na;
            *(float4*)(&shx[buf ^ 1][r1 * 64 + c1 * 4]) = nc;
        }
        __syncthreads();
    }
    #pragma unroll
    for (int m = 0; m < 4; ++m) {
        int mo = ocg * 16 + oc0l + m;
        float s = gamma[mo] * rsqrtf(var[mo] + EPSF);
        float r = acc[m] * s + (beta[mo] - mean[mo] * s);
        comp[(b * 64 + mo) * 4096 + px0 + lane] = fmaxf(r, 0.f);
    }
}

// ---------------- K2: split-K conv3x3 partials (R14 form — best measured) ----
// 5 oc/block (weight slice 2.88 KB; 5 resident slices < 16 KB K$ — R16 proved
// 10 oc thrashes K$: VALUBusy 82%->13%, 23us->60us). Tile 8x64 full-width,
// 256 threads, grid (8,80,2) = 5 blocks/CU balanced. Hoisted goff + f32x2 acc.
__global__ void k2_enc_part(const float* __restrict__ comp, const float* __restrict__ w,
                            float* __restrict__ encp) {
    __shared__ float sh[8 * 660];               // 8 planes of 10x66 = 21.1 KB
    const int tile = blockIdx.x;                // 0..7: 8 row-tiles (full width)
    const int og   = blockIdx.y >> 2;           // 0..19 (5 oc each)
    const int icc  = blockIdx.y & 3;            // 0..3  (16 ic each)
    const int b    = blockIdx.z;
    const int ty0 = tile << 3;                  // 0,8,...,56
    const int tid = threadIdx.x;
    const int tx = tid & 31, ty = tid >> 5;     // col-pair 0..31, row 0..7
    const int o0 = og * 5;

    int goff[21];                               // hoisted staging offsets
    #pragma unroll
    for (int k = 0; k < 21; ++k) {
        int idx = tid + k * 256;
        int off = -1;
        if (idx < 5280) {
            int ic_l = idx / 660;
            int rem  = idx - ic_l * 660;
            int r = rem / 66;
            int c = rem - r * 66;
            int gy = ty0 + r - 1;
            int gx = c - 1;
            if (gy >= 0 && gy < 64 && gx >= 0 && gx < 64)
                off = (ic_l << 12) + (gy << 6) + gx;
        }
        goff[k] = off;
    }

    f32x2 acc2[5];
    #pragma unroll
    for (int i = 0; i < 5; ++i) acc2[i] = (f32x2){0.f, 0.f};

    for (int ics = 0; ics < 2; ++ics) {
        if (ics) __syncthreads();
        const float* cb = comp + (b * 64 + icc * 16 + ics * 8) * 4096;
        #pragma unroll
        for (int k = 0; k < 21; ++k) {
            int idx = tid + k * 256;
            float v = 0.f;
            if (goff[k] >= 0) v = cb[goff[k]];
            if (idx < 5280) sh[idx] = v;
        }
        __syncthreads();

        #pragma unroll 2
        for (int ic_l = 0; ic_l < 8; ++ic_l) {
            const float* base = sh + ic_l * 660 + ty * 66 + 2 * tx;
            float t[3][4];
            #pragma unroll
            for (int dy = 0; dy < 3; ++dy)
                #pragma unroll
                for (int dx = 0; dx < 4; ++dx)
                    t[dy][dx] = base[dy * 66 + dx];
            f32x2 t2[3][3];
            #pragma unroll
            for (int dy = 0; dy < 3; ++dy)
                #pragma unroll
                for (int dx = 0; dx < 3; ++dx)
                    t2[dy][dx] = (f32x2){t[dy][dx], t[dy][dx + 1]};
            const int ic = icc * 16 + ics * 8 + ic_l;
            #pragma unroll
            for (int o_l = 0; o_l < 5; ++o_l) {
                const float* wp = w + ((o0 + o_l) * 64 + ic) * 9;   // uniform -> s_load
                f32x2 a = acc2[o_l];
                #pragma unroll
                for (int dy = 0; dy < 3; ++dy)
                    #pragma unroll
                    for (int dx = 0; dx < 3; ++dx)
                        a += wp[dy * 3 + dx] * t2[dy][dx];
                acc2[o_l] = a;
            }
        }
    }
    const int pix = ((ty0 + ty) << 6) + 2 * tx;
    #pragma unroll
    for (int o_l = 0; o_l < 5; ++o_l) {
        float2 v = {acc2[o_l].x, acc2[o_l].y};
        *(float2*)(&encp[((icc * 2 + b) * 100 + o0 + o_l) * 4096 + pix]) = v;
    }
}

// ---------------- K3: sum partials + BN + pixel-shuffle + softmax (R8) -------
__global__ void k3_softmax(const float* __restrict__ encp,
                           const float* __restrict__ gamma, const float* __restrict__ beta,
                           const float* __restrict__ mean, const float* __restrict__ var,
                           bf16* __restrict__ Wsm) {
    __shared__ float red[2][5][64];
    const int tid  = threadIdx.x;
    const int lane = tid & 63, wv = tid >> 6;   // wv 0..4
    const int item = blockIdx.x * 64 + lane;    // 0..32767
    const int pos = item & 4095;
    const int g   = (item >> 12) & 3;           // block-uniform
    const int b   = item >> 14;                 // block-uniform
    const int kbase = wv * 5;                   // 0,5,10,15,20
    const size_t ICS = (size_t)200 * 4096;      // icc stride in encp

    float L[5][4];
    #pragma unroll
    for (int q = 0; q < 5; ++q) {               // branch-free: loads all hoist
        const int o = (kbase + q) * 4 + g;
        const float* ep = encp + ((size_t)b * 100 + o) * 4096 + pos;
        L[q][0] = ep[0];
        L[q][1] = ep[ICS];
        L[q][2] = ep[2 * ICS];
        L[q][3] = ep[3 * ICS];
    }
    float v[5];
    float mx = -1e30f;
    #pragma unroll
    for (int q = 0; q < 5; ++q) {
        const int o = (kbase + q) * 4 + g;
        float a = ((L[q][0] + L[q][1]) + L[q][2]) + L[q][3];
        float s = gamma[o] * rsqrtf(var[o] + EPSF);
        v[q] = a * s + (beta[o] - mean[o] * s);
        mx = fmaxf(mx, v[q]);
    }
    red[0][wv][lane] = mx;
    __syncthreads();
    mx = fmaxf(fmaxf(fmaxf(red[0][0][lane], red[0][1][lane]),
                     fmaxf(red[0][2][lane], red[0][3][lane])), red[0][4][lane]);
    float s = 0.f;
    #pragma unroll
    for (int q = 0; q < 5; ++q) { v[q] = __expf(v[q] - mx); s += v[q]; }
    red[1][wv][lane] = s;
    __syncthreads();
    s = (((red[1][0][lane] + red[1][1][lane]) + red[1][2][lane])
         + red[1][3][lane]) + red[1][4][lane];
    const float inv = 1.f / s;
    bf16* o_ = Wsm + ((size_t)(b * 4 + g) * 25 + kbase) * 4096 + pos;
    #pragma unroll
    for (int q = 0; q < 5; ++q) o_[q * 4096] = __float2bfloat16(v[q] * inv);
}

// ---------------- K4: weighted gather (R12 nt-store form, unchanged) ---------
__global__ void k4_gather(const float* __restrict__ x, const bf16* __restrict__ Wsm,
                          float* __restrict__ out) {
    __shared__ float4 patch[8 * 36];            // 4.6 KB
    const int tile   = blockIdx.x;              // 0..31: tileY 0..15, tileX 0..1
    const int cchunk = blockIdx.y;              // 0..31 (8 channels each)
    const int b      = blockIdx.z;
    const int ly0 = (tile >> 1) << 2;           // 0,4,...,60
    const int lx0 = (tile & 1) << 5;            // 0,32
    const int tid = threadIdx.x;
    const int ph = tid >> 7;
    const int r  = tid & 127;
    const int ly = r >> 5, lx = r & 31;
    const int yl = ly0 + ly, xl = lx0 + lx;

    float w0[25], w1[25];
    {
        const bf16* wp0 = Wsm + ((b * 4 + ph * 2    ) * 25) * 4096 + yl * 64 + xl;
        const bf16* wp1 = Wsm + ((b * 4 + ph * 2 + 1) * 25) * 4096 + yl * 64 + xl;
        #pragma unroll
        for (int k = 0; k < 25; ++k) {
            w0[k] = __bfloat162float(wp0[k * 4096]);
            w1[k] = __bfloat162float(wp1[k * 4096]);
        }
    }

    for (int cg = 0; cg < 2; ++cg) {
        const int c0 = cchunk * 8 + cg * 4;
        for (int idx = tid; idx < 8 * 36; idx += 256) {
            int pr = idx / 36, pc = idx - (idx / 36) * 36;
            int gy = ly0 - 2 + pr, gx = lx0 - 2 + pc;
            float4 v = {0.f, 0.f, 0.f, 0.f};
            if (gy >= 0 && gy < 64 && gx >= 0 && gx < 64) {
                const float* xp = x + ((b * 256 + c0) * 4096) + gy * 64 + gx;
                v.x = xp[0]; v.y = xp[4096]; v.z = xp[8192]; v.w = xp[12288];
            }
            patch[idx] = v;
        }
        __syncthreads();
        float4 a0 = {0.f, 0.f, 0.f, 0.f};
        float4 a1 = {0.f, 0.f, 0.f, 0.f};
        #pragma unroll
        for (int i = 0; i < 5; ++i) {
            #pragma unroll
            for (int j = 0; j < 5; ++j) {
                float4 xv = patch[(ly + i) * 36 + (lx + j)];
                float wa = w0[i * 5 + j], wb = w1[i * 5 + j];
                a0.x += wa * xv.x; a0.y += wa * xv.y; a0.z += wa * xv.z; a0.w += wa * xv.w;
                a1.x += wb * xv.x; a1.y += wb * xv.y; a1.z += wb * xv.z; a1.w += wb * xv.w;
            }
        }
        float* ob = out + (size_t)(b * 256 + c0) * 16384 + (2 * yl + ph) * 128 + 2 * xl;
        f32x2 s0 = {a0.x, a1.x};
        f32x2 s1 = {a0.y, a1.y};
        f32x2 s2 = {a0.z, a1.z};
        f32x2 s3 = {a0.w, a1.w};
        __builtin_nontemporal_store(s0, (f32x2*)(ob));
        __builtin_nontemporal_store(s1, (f32x2*)(ob + 16384));
        __builtin_nontemporal_store(s2, (f32x2*)(ob + 32768));
        __builtin_nontemporal_store(s3, (f32x2*)(ob + 49152));
        if (cg == 0) __syncthreads();
    }
}

extern "C" void kernel_launch(void* const* d_in, const int* in_sizes, int n_in,
                              void* d_out, int out_size, void* d_ws, size_t ws_size,
                              hipStream_t stream) {
    const float* x          = (const float*)d_in[0];
    const float* comp_w     = (const float*)d_in[1];
    const float* comp_gamma = (const float*)d_in[2];
    const float* comp_beta  = (const float*)d_in[3];
    const float* comp_mean  = (const float*)d_in[4];
    const float* comp_var   = (const float*)d_in[5];
    const float* enc_w      = (const float*)d_in[6];
    const float* enc_gamma  = (const float*)d_in[7];
    const float* enc_beta   = (const float*)d_in[8];
    const float* enc_mean   = (const float*)d_in[9];
    const float* enc_var    = (const float*)d_in[10];
    float* out = (float*)d_out;

    float* ws   = (float*)d_ws;
    float* comp = ws;                             // 2*64*4096    =  524288 floats
    float* encp = ws + 524288;                    // 4*2*100*4096 = 3276800 floats
    bf16*  Wsm  = (bf16*)(ws + 524288 + 3276800); // 2*4*25*4096 bf16

    k1_comp<<<dim3(64, 4, 2), dim3(256), 0, stream>>>(x, comp_w, comp_gamma, comp_beta,
                                                      comp_mean, comp_var, comp);
    k2_enc_part<<<dim3(8, 80, 2), dim3(256), 0, stream>>>(comp, enc_w, encp);
    k3_softmax<<<dim3(512), dim3(320), 0, stream>>>(encp, enc_gamma, enc_beta,
                                                    enc_mean, enc_var, Wsm);
    k4_gather<<<dim3(32, 32, 2), dim3(256), 0, stream>>>(x, Wsm, out);
}